// Round 1
// baseline (5494.728 us; speedup 1.0000x reference)
//
#include <hip/hip_runtime.h>

#define HDIM 2048
#define TSTEPS 1024
#define NBLK 256
#define NTHR 512
#define TAGM 0x3FFu

typedef unsigned long long ull;

__device__ __forceinline__ int snake_src(int t) {
    int y = t >> 5, p = t & 31;
    return (y & 1) ? (y * 32 + 31 - p) : t;
}
__device__ __forceinline__ float sigmoid_f(float v) {
    return __builtin_amdgcn_rcpf(1.f + __expf(-v));
}
__device__ __forceinline__ float tanh_f(float v) {
    return 1.f - 2.f * __builtin_amdgcn_rcpf(__expf(2.f * v) + 1.f);
}

// ---------------------------------------------------------------------------
// Wave-per-column restructure of the proven tag-in-mantissa design.
//   - wave w of block b owns column b*8+w; lane l owns rows k*256+4l+j
//     (j=0..3, k=0..7)  -> 96 recurrent weights in registers, as before.
//   - ONE __syncthreads per step (was 3): h is double-buffered in LDS
//     (stage of step t+1 writes hb[(t+1)&1] while stragglers still read
//     hb[t&1]; a wave cannot get 2 steps ahead of the single barrier).
//   - cross-wave reduce eliminated: 6-stage 64-lane butterfly leaves the
//     full dot products in ALL lanes; gates computed uniformly; only the
//     tagged publish is lane-0 predicated. No `red` buffer, no serial sum.
//   - LDS conflict-free: stage = one b128 write/thread at [4*tid];
//     compute = 8 b128 reads/lane at [k*256+4*lane] (consecutive lanes ->
//     consecutive 16B).
//   - x[snake(t)] preloaded to LDS (sX) -> off the critical path.
//   - publish packs tag with ROUND-to-nearest (+512 before masking low 10
//     bits): per-hop quantization error 2^-14 rel instead of 2^-13.
// Protocol identical to the 2554us kernel: 4B f32 slots, 10-bit step tag in
// low mantissa, parity double buffer u0/u1. Poison 0xAA..: low10 = 682, but
// every slot is rewritten every step long before t=682 - no false match.
// ---------------------------------------------------------------------------
__global__ __launch_bounds__(NTHR, 2) void gru_all(
    const float* __restrict__ x,
    const float* __restrict__ We,  const float* __restrict__ be,
    const float* __restrict__ Wir, const float* __restrict__ bir,
    const float* __restrict__ Wiz, const float* __restrict__ biz,
    const float* __restrict__ Win, const float* __restrict__ bin_,
    const float* __restrict__ Whr, const float* __restrict__ Whz,
    const float* __restrict__ Whn, const float* __restrict__ bhn,
    float* __restrict__ out, unsigned* __restrict__ u0, unsigned* __restrict__ u1)
{
    const int tid  = threadIdx.x;
    const int blk  = blockIdx.x;
    const int lane = tid & 63;
    const int wv   = tid >> 6;              // 0..7
    const int col  = blk * 8 + wv;          // this wave's column

    __shared__ __align__(16) float hb[2][HDIM];   // double-buffered h_t
    __shared__ float sX[TSTEPS];                  // x in snake order

    // ---- x into LDS (one-time) ----
    for (int i = tid; i < TSTEPS; i += NTHR) sX[i] = x[snake_src(i)];

    // ---- recurrent weights into registers (one-time; column-scattered) ----
    float wr[32], wz[32], wn[32];
#pragma unroll
    for (int k = 0; k < 8; ++k) {
#pragma unroll
        for (int j = 0; j < 4; ++j) {
            size_t off = (size_t)(k * 256 + lane * 4 + j) * HDIM + col;
            wr[k * 4 + j] = Whr[off];
            wz[k * 4 + j] = Whz[off];
            wn[k * 4 + j] = Whn[off];
        }
    }

    // ---- rank-1 input-path constants; butterfly -> ALL lanes hold them ----
    float eR = 0, eZ = 0, eN = 0, bR = 0, bZ = 0, bN = 0;
#pragma unroll 4
    for (int k = 0; k < 32; ++k) {
        int row = k * 64 + lane;
        float we = We[row], bb = be[row];
        size_t off = (size_t)row * HDIM + col;
        float w0 = Wir[off], w1 = Wiz[off], w2 = Win[off];
        eR = fmaf(we, w0, eR);  bR = fmaf(bb, w0, bR);
        eZ = fmaf(we, w1, eZ);  bZ = fmaf(bb, w1, bZ);
        eN = fmaf(we, w2, eN);  bN = fmaf(bb, w2, bN);
    }
#pragma unroll
    for (int m = 1; m < 64; m <<= 1) {
        eR += __shfl_xor(eR, m, 64); eZ += __shfl_xor(eZ, m, 64);
        eN += __shfl_xor(eN, m, 64); bR += __shfl_xor(bR, m, 64);
        bZ += __shfl_xor(bZ, m, 64); bN += __shfl_xor(bN, m, 64);
    }
    const float vrc = eR, vzc = eZ, vnc = eN;
    const float crc = bR + bir[col];
    const float czc = bZ + biz[col];
    const float cnc = bN + bin_[col];
    const float bhc = bhn[col];

    __syncthreads();                        // sX staged

    // ---- step 0: h_0 == 0, fully local; publish h_1 with tag 1 ----
    {
        float x0 = sX[0];
        float ar = fmaf(x0, vrc, crc);
        float az = fmaf(x0, vzc, czc);
        float an = fmaf(x0, vnc, cnc);
        float rg = sigmoid_f(ar), zg = sigmoid_f(az);
        float ng = tanh_f(fmaf(rg, bhc, an));
        float h1 = (1.f - zg) * ng;
        if (lane == 0) {
            unsigned pk = ((__float_as_uint(h1) + 512u) & ~TAGM) | 1u;
            __hip_atomic_store(&u1[col], pk, __ATOMIC_RELAXED, __HIP_MEMORY_SCOPE_AGENT);
        }
    }

    const ull M2 = 0x000003FF000003FFull;   // tag mask in both halves

    for (int t = 1; t < TSTEPS; ++t) {
        const unsigned* pin  = (t & 1) ? u1 : u0;
        unsigned*       pout = (t & 1) ? u0 : u1;
        const unsigned  tg   = (unsigned)t & TAGM;
        const ull       tg2  = ((ull)tg << 32) | (ull)tg;

        // ---- poll fused tag-in-mantissa slots: 2x8B loads = 4 values ----
        const ull* pp = (const ull*)pin + 2 * tid;
        ull v0, v1;
        for (;;) {
            v0 = __hip_atomic_load(&pp[0], __ATOMIC_RELAXED, __HIP_MEMORY_SCOPE_AGENT);
            v1 = __hip_atomic_load(&pp[1], __ATOMIC_RELAXED, __HIP_MEMORY_SCOPE_AGENT);
            if (!(((v0 ^ tg2) | (v1 ^ tg2)) & M2)) break;
        }
        float* hc = hb[t & 1];
        float4 hq = make_float4(__uint_as_float((unsigned)v0         & ~TAGM),
                                __uint_as_float((unsigned)(v0 >> 32) & ~TAGM),
                                __uint_as_float((unsigned)v1         & ~TAGM),
                                __uint_as_float((unsigned)(v1 >> 32) & ~TAGM));
        *(float4*)&hc[tid * 4] = hq;
        __syncthreads();                    // the ONLY barrier per step

        float hold = hc[col];               // broadcast read
        float xt   = sX[t];

        // ---- 96 register-resident FMAs, conflict-free b128 LDS reads ----
        float a0 = 0.f, a1 = 0.f, a2 = 0.f;
#pragma unroll
        for (int k = 0; k < 8; ++k) {
            float4 h4 = *(const float4*)&hc[k * 256 + lane * 4];
            a0 = fmaf(h4.x, wr[k*4+0], a0); a1 = fmaf(h4.x, wz[k*4+0], a1); a2 = fmaf(h4.x, wn[k*4+0], a2);
            a0 = fmaf(h4.y, wr[k*4+1], a0); a1 = fmaf(h4.y, wz[k*4+1], a1); a2 = fmaf(h4.y, wn[k*4+1], a2);
            a0 = fmaf(h4.z, wr[k*4+2], a0); a1 = fmaf(h4.z, wz[k*4+2], a1); a2 = fmaf(h4.z, wn[k*4+2], a2);
            a0 = fmaf(h4.w, wr[k*4+3], a0); a1 = fmaf(h4.w, wz[k*4+3], a1); a2 = fmaf(h4.w, wn[k*4+3], a2);
        }

        // ---- 6-stage butterfly: full sums land in every lane ----
#pragma unroll
        for (int m = 1; m < 64; m <<= 1) {
            a0 += __shfl_xor(a0, m, 64);
            a1 += __shfl_xor(a1, m, 64);
            a2 += __shfl_xor(a2, m, 64);
        }

        // ---- gates computed uniformly; only the publish is predicated ----
        float ar = fmaf(xt, vrc, crc) + a0;
        float az = fmaf(xt, vzc, czc) + a1;
        float an = fmaf(xt, vnc, cnc);
        float rg = sigmoid_f(ar), zg = sigmoid_f(az);
        float ng = tanh_f(an + rg * (a2 + bhc));
        float hnew = (1.f - zg) * ng + zg * hold;

        if (t == TSTEPS - 1) {
            if (lane == 0) out[col] = hnew;
        } else if (lane == 0) {
            unsigned pk = ((__float_as_uint(hnew) + 512u) & ~TAGM)
                        | ((unsigned)(t + 1) & TAGM);
            __hip_atomic_store(&pout[col], pk, __ATOMIC_RELAXED, __HIP_MEMORY_SCOPE_AGENT);
        }
        // no trailing barrier: step t+1 stages into hb[(t+1)&1]
    }
}

extern "C" void kernel_launch(void* const* d_in, const int* in_sizes, int n_in,
                              void* d_out, int out_size, void* d_ws, size_t ws_size,
                              hipStream_t stream) {
    const float* x    = (const float*)d_in[0];
    const float* We   = (const float*)d_in[1];
    const float* be   = (const float*)d_in[2];
    const float* Wir  = (const float*)d_in[3];
    const float* bir  = (const float*)d_in[4];
    const float* Wiz  = (const float*)d_in[5];
    const float* biz  = (const float*)d_in[6];
    const float* Win  = (const float*)d_in[7];
    const float* bin_ = (const float*)d_in[8];
    const float* Whr  = (const float*)d_in[9];
    const float* Whz  = (const float*)d_in[10];
    const float* Whn  = (const float*)d_in[11];
    const float* bhn  = (const float*)d_in[12];

    unsigned* u0 = (unsigned*)d_ws;        // even-parity slots (2048 x 4B)
    unsigned* u1 = u0 + HDIM;              // odd-parity slots

    gru_all<<<NBLK, NTHR, 0, stream>>>(x, We, be, Wir, bir, Wiz, biz, Win, bin_,
                                       Whr, Whz, Whn, bhn,
                                       (float*)d_out, u0, u1);
}

// Round 2
// 2884.314 us; speedup vs baseline: 1.9050x; 1.9050x over previous
//
#include <hip/hip_runtime.h>

#define HDIM 2048
#define TSTEPS 1024
#define NBLK 256
#define NTHR 512
#define CPB 8
#define TAGM 0x3FFu

typedef unsigned long long ull;

__device__ __forceinline__ int snake_src(int t) {
    int y = t >> 5, p = t & 31;
    return (y & 1) ? (y * 32 + 31 - p) : t;
}
__device__ __forceinline__ float sigmoid_f(float v) {
    return __builtin_amdgcn_rcpf(1.f + __expf(-v));
}
__device__ __forceinline__ float tanh_f(float v) {
    return 1.f - 2.f * __builtin_amdgcn_rcpf(__expf(2.f * v) + 1.f);
}

// ---------------------------------------------------------------------------
// R2 = proven R0 structure (block owns 8 columns; wave-0 coalesced 32B
// tagged publish; tag-in-mantissa parity buffers u0/u1) with four
// protocol-preserving critical-path cuts:
//   1. BAR3 removed: lds_h and red are parity double-buffered. Run-ahead
//      waves write only the par^1 buffers and are self-throttled by the
//      poll (can't detect t+1 before wave0's publish). 2 barriers/step.
//   2. finalize cross-wave sum parallelized: wave0 does 3 LDS reads +
//      3-stage shfl_xor (stride 8/16/32) instead of 8 threads x 24 serial
//      LDS reads.
//   3. x preloaded to LDS (sX); next-step input terms a{r,z,n}_pre
//      precomputed AFTER the publish store (off critical path).
//   4. hold prefetched right after BAR1.
// Publish: round-to-nearest tag pack ((bits+512)&~TAGM)|tag, per-hop rel
// error <= 2^-14. Poison 0xAA..: low10=682; the t=682 parity buffer has
// been rewritten 340 times by then — no false match.
// ---------------------------------------------------------------------------
__global__ __launch_bounds__(NTHR, 2) void gru_all(
    const float* __restrict__ x,
    const float* __restrict__ We,  const float* __restrict__ be,
    const float* __restrict__ Wir, const float* __restrict__ bir,
    const float* __restrict__ Wiz, const float* __restrict__ biz,
    const float* __restrict__ Win, const float* __restrict__ bin_,
    const float* __restrict__ Whr, const float* __restrict__ Whz,
    const float* __restrict__ Whn, const float* __restrict__ bhn,
    float* __restrict__ out, unsigned* __restrict__ u0, unsigned* __restrict__ u1)
{
    const int tid  = threadIdx.x;
    const int blk  = blockIdx.x;
    const int c    = tid & 7;
    const int r    = tid >> 3;            // 0..63
    const int col  = blk * CPB + c;
    const int row0 = r * 32;
    const int lane = tid & 63, wv = tid >> 6;

    // padded layout: i -> i + ((i>>6)<<2); buffer stride 2176 floats
    __shared__ __align__(16) float hb[2][2176];
    __shared__ float red[2][8][3][8];
    __shared__ float sX[TSTEPS];

    // ---- one-time staging: We -> hb[0], be -> hb[1], x(snake) -> sX ----
    for (int i = tid; i < HDIM; i += NTHR) { hb[0][i] = We[i]; hb[1][i] = be[i]; }
    for (int i = tid; i < TSTEPS; i += NTHR) sX[i] = x[snake_src(i)];
    __syncthreads();

    // ---- recurrent weights into registers (one-time) ----
    float wr[32], wz[32], wn[32];
#pragma unroll
    for (int k = 0; k < 32; ++k) {
        size_t off = (size_t)(row0 + k) * HDIM + col;
        wr[k] = Whr[off];
        wz[k] = Whz[off];
        wn[k] = Whn[off];
    }

    // ---- rank-1 input-path constants for this block's 8 columns ----
    float eR=0,eZ=0,eN=0,bRa=0,bZa=0,bNa=0;
#pragma unroll 8
    for (int k = 0; k < 32; ++k) {
        size_t off = (size_t)(row0 + k) * HDIM + col;
        float we = hb[0][row0 + k], bb = hb[1][row0 + k];
        float w0 = Wir[off], w1 = Wiz[off], w2 = Win[off];
        eR  = fmaf(we, w0, eR);  bRa = fmaf(bb, w0, bRa);
        eZ  = fmaf(we, w1, eZ);  bZa = fmaf(bb, w1, bZa);
        eN  = fmaf(we, w2, eN);  bNa = fmaf(bb, w2, bNa);
    }
#pragma unroll
    for (int m = 8; m < 64; m <<= 1) {
        eR  += __shfl_xor(eR,  m, 64); eZ  += __shfl_xor(eZ,  m, 64);
        eN  += __shfl_xor(eN,  m, 64); bRa += __shfl_xor(bRa, m, 64);
        bZa += __shfl_xor(bZa, m, 64); bNa += __shfl_xor(bNa, m, 64);
    }
    if (lane < 8) {
        red[0][wv][0][lane]=eR;  red[0][wv][1][lane]=eZ;  red[0][wv][2][lane]=eN;
        red[1][wv][0][lane]=bRa; red[1][wv][1][lane]=bZa; red[1][wv][2][lane]=bNa;
    }
    __syncthreads();   // also fences hb(We/be) reads before hb reuse as h-buf

    float vrc=0,vzc=0,vnc=0,crc=0,czc=0,cnc=0,bhc=0;
    float aR=0, aZ=0, aN=0;               // precomputed input terms (tid<8)
    if (tid < 8) {
#pragma unroll
        for (int w = 0; w < 8; ++w) {
            vrc += red[0][w][0][tid]; vzc += red[0][w][1][tid]; vnc += red[0][w][2][tid];
            crc += red[1][w][0][tid]; czc += red[1][w][1][tid]; cnc += red[1][w][2][tid];
        }
        crc += bir[col]; czc += biz[col]; cnc += bin_[col];
        bhc = bhn[col];

        // ---- step 0: h_0 == 0, fully local; publish h_1 with tag 1 ----
        float x0 = sX[0];
        float ar = fmaf(x0, vrc, crc);
        float az = fmaf(x0, vzc, czc);
        float an = fmaf(x0, vnc, cnc);
        float rg = sigmoid_f(ar), zg = sigmoid_f(az);
        float ng = tanh_f(fmaf(rg, bhc, an));
        float h1 = (1.f - zg) * ng;
        unsigned pk = ((__float_as_uint(h1) + 512u) & ~TAGM) | 1u;
        __hip_atomic_store(&u1[col], pk, __ATOMIC_RELAXED, __HIP_MEMORY_SCOPE_AGENT);

        // precompute input terms for t=1 (off critical path)
        float x1 = sX[1];
        aR = fmaf(x1, vrc, crc);
        aZ = fmaf(x1, vzc, czc);
        aN = fmaf(x1, vnc, cnc);
    }

    const int sbase = tid * 4;
    const int lwb   = sbase + ((sbase >> 6) << 2);  // padded write base
    const int lrb   = row0  + ((row0  >> 6) << 2);  // padded read base
    const int pcol  = col   + ((col   >> 6) << 2);
    const ull  M2   = 0x000003FF000003FFull;

    for (int t = 1; t < TSTEPS; ++t) {
        const int par = t & 1;
        const unsigned* pin  = par ? u1 : u0;
        unsigned*       pout = par ? u0 : u1;
        const unsigned  tg   = (unsigned)t & TAGM;
        const ull       tg2  = ((ull)tg << 32) | (ull)tg;

        // ---- poll fused tag-in-mantissa slots: 2x8B loads = 4 values ----
        const ull* pp = (const ull*)pin + 2 * tid;
        ull v0, v1;
        for (;;) {
            v0 = __hip_atomic_load(&pp[0], __ATOMIC_RELAXED, __HIP_MEMORY_SCOPE_AGENT);
            v1 = __hip_atomic_load(&pp[1], __ATOMIC_RELAXED, __HIP_MEMORY_SCOPE_AGENT);
            if (!(((v0 ^ tg2) | (v1 ^ tg2)) & M2)) break;
        }
        float* hc = hb[par];
        float4 hq = make_float4(__uint_as_float((unsigned)v0         & ~TAGM),
                                __uint_as_float((unsigned)(v0 >> 32) & ~TAGM),
                                __uint_as_float((unsigned)v1         & ~TAGM),
                                __uint_as_float((unsigned)(v1 >> 32) & ~TAGM));
        *(float4*)&hc[lwb] = hq;
        __syncthreads();                          // BAR1: h_t staged

        float hold = 0.f;
        if (wv == 0) hold = hc[pcol];             // prefetch for finalize

        // ---- 96 register-resident FMAs ----
        float a0 = 0.f, a1 = 0.f, a2 = 0.f;
#pragma unroll
        for (int k = 0; k < 32; ++k) {
            float hv = hc[lrb + k];
            a0 = fmaf(hv, wr[k], a0);
            a1 = fmaf(hv, wz[k], a1);
            a2 = fmaf(hv, wn[k], a2);
        }
#pragma unroll
        for (int m = 8; m < 64; m <<= 1) {
            a0 += __shfl_xor(a0, m, 64);
            a1 += __shfl_xor(a1, m, 64);
            a2 += __shfl_xor(a2, m, 64);
        }
        if (lane < 8) { red[par][wv][0][lane]=a0; red[par][wv][1][lane]=a1; red[par][wv][2][lane]=a2; }
        __syncthreads();                          // BAR2: partials ready

        // ---- wave0: parallel cross-wave reduce + finalize + publish ----
        if (wv == 0) {
            const int w  = lane >> 3, cc = lane & 7;
            float s0 = red[par][w][0][cc];
            float s1 = red[par][w][1][cc];
            float s2 = red[par][w][2][cc];
#pragma unroll
            for (int m = 8; m < 64; m <<= 1) {
                s0 += __shfl_xor(s0, m, 64);
                s1 += __shfl_xor(s1, m, 64);
                s2 += __shfl_xor(s2, m, 64);
            }
            if (lane < 8) {
                float ar = aR + s0;
                float az = aZ + s1;
                float an = aN;
                float rg = sigmoid_f(ar), zg = sigmoid_f(az);
                float ng = tanh_f(an + rg * (s2 + bhc));
                float hnew = (1.f - zg) * ng + zg * hold;
                if (t == TSTEPS - 1) {
                    out[col] = hnew;
                } else {
                    unsigned pk = ((__float_as_uint(hnew) + 512u) & ~TAGM)
                                | ((unsigned)(t + 1) & TAGM);
                    __hip_atomic_store(&pout[col], pk, __ATOMIC_RELAXED, __HIP_MEMORY_SCOPE_AGENT);
                    // precompute input terms for t+1 (after publish, off path)
                    float xn = sX[t + 1];
                    aR = fmaf(xn, vrc, crc);
                    aZ = fmaf(xn, vzc, czc);
                    aN = fmaf(xn, vnc, cnc);
                }
            }
        }
        // no BAR3: step t+1 stages into hb[par^1] / red[par^1]; run-ahead
        // waves are self-throttled by the poll (needs wave0's publish).
    }
}

extern "C" void kernel_launch(void* const* d_in, const int* in_sizes, int n_in,
                              void* d_out, int out_size, void* d_ws, size_t ws_size,
                              hipStream_t stream) {
    const float* x    = (const float*)d_in[0];
    const float* We   = (const float*)d_in[1];
    const float* be   = (const float*)d_in[2];
    const float* Wir  = (const float*)d_in[3];
    const float* bir  = (const float*)d_in[4];
    const float* Wiz  = (const float*)d_in[5];
    const float* biz  = (const float*)d_in[6];
    const float* Win  = (const float*)d_in[7];
    const float* bin_ = (const float*)d_in[8];
    const float* Whr  = (const float*)d_in[9];
    const float* Whz  = (const float*)d_in[10];
    const float* Whn  = (const float*)d_in[11];
    const float* bhn  = (const float*)d_in[12];

    unsigned* u0 = (unsigned*)d_ws;        // even-parity slots (2048 x 4B)
    unsigned* u1 = u0 + HDIM;              // odd-parity slots

    gru_all<<<NBLK, NTHR, 0, stream>>>(x, We, be, Wir, bir, Wiz, biz, Win, bin_,
                                       Whr, Whz, Whn, bhn,
                                       (float*)d_out, u0, u1);
}

// Round 3
// 2256.960 us; speedup vs baseline: 2.4346x; 1.2780x over previous
//
#include <hip/hip_runtime.h>

#define HDIM 2048
#define TSTEPS 1024
#define NBLK 256
#define NTHR 512
#define CPB 8
#define TAGM 0x3FFu
#define NREP 8
#define RSTRIDE 2112u   // u32 per replica = 8KB + 256B (channel decorrelation)

typedef unsigned long long ull;

__device__ __forceinline__ int snake_src(int t) {
    int y = t >> 5, p = t & 31;
    return (y & 1) ? (y * 32 + 31 - p) : t;
}
__device__ __forceinline__ float sigmoid_f(float v) {
    return __builtin_amdgcn_rcpf(1.f + __expf(-v));
}
__device__ __forceinline__ float tanh_f(float v) {
    return 1.f - 2.f * __builtin_amdgcn_rcpf(__expf(2.f * v) + 1.f);
}

// ---------------------------------------------------------------------------
// R3 = exact R0 step structure (3 barriers; tid<8 serial 24-read finalize;
// coalesced wave-0 tagged publish; tag-in-mantissa parity buffers) plus
// contention attacks on the publish/poll hot region:
//   1. Publish replicated 8x: wave0's 64 lanes store pk for column (lane&7)
//      into replica (lane>>3) — ONE store instruction, 8 parallel 32B
//      transactions at 8448B stride (distinct channel lines). Consumers
//      poll ONLY replica (blk&7) (== XCD id under round-robin dispatch) ->
//      per-channel poll load / 8.
//   2. Poll backoff: first check immediate, then s_sleep(1) between
//      retries — cuts spin request rate, <=64cyc detect jitter.
//   3. Off-critical-path cuts kept from R2 (safe with BAR3 restored):
//      sX preload, post-publish precompute of a{r,z,n}, post-BAR1 hold
//      prefetch. We/be read direct from global in one-time init.
// Publish packs tag round-to-nearest: rel err <= 2^-14/hop. Poison 0xAA..:
// low10=682; that parity buffer is rewritten 340x before t=682 — no false
// match (per replica, since all replicas are rewritten every publish).
// ---------------------------------------------------------------------------
__global__ __launch_bounds__(NTHR, 2) void gru_all(
    const float* __restrict__ x,
    const float* __restrict__ We,  const float* __restrict__ be,
    const float* __restrict__ Wir, const float* __restrict__ bir,
    const float* __restrict__ Wiz, const float* __restrict__ biz,
    const float* __restrict__ Win, const float* __restrict__ bin_,
    const float* __restrict__ Whr, const float* __restrict__ Whz,
    const float* __restrict__ Whn, const float* __restrict__ bhn,
    float* __restrict__ out, unsigned* __restrict__ u0, unsigned* __restrict__ u1)
{
    const int tid  = threadIdx.x;
    const int blk  = blockIdx.x;
    const int c    = tid & 7;
    const int r    = tid >> 3;            // 0..63
    const int col  = blk * CPB + c;
    const int row0 = r * 32;
    const int lane = tid & 63, wv = tid >> 6;

    __shared__ __align__(16) float lds_h[2304];   // pad: i -> i + ((i>>6)<<2)
    __shared__ float red[8][6][8];
    __shared__ float sX[TSTEPS];

    // ---- one-time: x (snake order) into LDS ----
    for (int i = tid; i < TSTEPS; i += NTHR) sX[i] = x[snake_src(i)];

    // ---- recurrent weights into registers (one-time) ----
    float wr[32], wz[32], wn[32];
#pragma unroll
    for (int k = 0; k < 32; ++k) {
        size_t off = (size_t)(row0 + k) * HDIM + col;
        wr[k] = Whr[off];
        wz[k] = Whz[off];
        wn[k] = Whn[off];
    }

    // ---- rank-1 input-path constants (We/be direct from global) ----
    float eR=0,eZ=0,eN=0,bRa=0,bZa=0,bNa=0;
#pragma unroll 8
    for (int k = 0; k < 32; ++k) {
        int row = row0 + k;
        size_t off = (size_t)row * HDIM + col;
        float we = We[row], bb = be[row];
        float w0 = Wir[off], w1 = Wiz[off], w2 = Win[off];
        eR  = fmaf(we, w0, eR);  bRa = fmaf(bb, w0, bRa);
        eZ  = fmaf(we, w1, eZ);  bZa = fmaf(bb, w1, bZa);
        eN  = fmaf(we, w2, eN);  bNa = fmaf(bb, w2, bNa);
    }
#pragma unroll
    for (int m = 8; m < 64; m <<= 1) {
        eR  += __shfl_xor(eR,  m, 64); eZ  += __shfl_xor(eZ,  m, 64);
        eN  += __shfl_xor(eN,  m, 64); bRa += __shfl_xor(bRa, m, 64);
        bZa += __shfl_xor(bZa, m, 64); bNa += __shfl_xor(bNa, m, 64);
    }
    if (lane < 8) {
        red[wv][0][lane]=eR;  red[wv][1][lane]=eZ;  red[wv][2][lane]=eN;
        red[wv][3][lane]=bRa; red[wv][4][lane]=bZa; red[wv][5][lane]=bNa;
    }
    __syncthreads();   // red + sX staged

    float vrc=0,vzc=0,vnc=0,crc=0,czc=0,cnc=0,bhc=0;
    float aR=0, aZ=0, aN=0;
    unsigned pk1 = 0;
    if (tid < 8) {
#pragma unroll
        for (int w = 0; w < 8; ++w) {
            vrc += red[w][0][tid]; vzc += red[w][1][tid]; vnc += red[w][2][tid];
            crc += red[w][3][tid]; czc += red[w][4][tid]; cnc += red[w][5][tid];
        }
        crc += bir[col]; czc += biz[col]; cnc += bin_[col];
        bhc = bhn[col];

        // ---- step 0: h_0 == 0, fully local; h_1 with tag 1 ----
        float x0 = sX[0];
        float ar = fmaf(x0, vrc, crc);
        float az = fmaf(x0, vzc, czc);
        float an = fmaf(x0, vnc, cnc);
        float rg = sigmoid_f(ar), zg = sigmoid_f(az);
        float ng = tanh_f(fmaf(rg, bhc, an));
        float h1 = (1.f - zg) * ng;
        pk1 = ((__float_as_uint(h1) + 512u) & ~TAGM) | 1u;

        // precompute input terms for t=1 (off critical path)
        float x1 = sX[1];
        aR = fmaf(x1, vrc, crc);
        aZ = fmaf(x1, vzc, czc);
        aN = fmaf(x1, vnc, cnc);
    }
    // replicated step-0 publish (init reads of red complete before this —
    // run-ahead waves are gated by the poll, which needs this publish)
    if (wv == 0) {
        unsigned pkb = __shfl(pk1, lane & 7, 64);
        __hip_atomic_store(&u1[(unsigned)(lane >> 3) * RSTRIDE + (unsigned)blk * 8u + (unsigned)(lane & 7)],
                           pkb, __ATOMIC_RELAXED, __HIP_MEMORY_SCOPE_AGENT);
    }

    const int sbase = tid * 4;
    const int lwb   = sbase + ((sbase >> 6) << 2);  // padded LDS write base
    const int lrb   = row0  + ((row0  >> 6) << 2);  // padded LDS read base
    const int pcol  = col   + ((col   >> 6) << 2);
    const ull  M2   = 0x000003FF000003FFull;
    const size_t repoff = (size_t)(blk & 7) * (RSTRIDE / 2);  // in ull units

    for (int t = 1; t < TSTEPS; ++t) {
        const unsigned* pin  = (t & 1) ? u1 : u0;
        unsigned*       pout = (t & 1) ? u0 : u1;
        const unsigned  tg   = (unsigned)t & TAGM;
        const ull       tg2  = ((ull)tg << 32) | (ull)tg;

        // ---- poll assigned replica: 2x8B loads = 4 tagged values ----
        const ull* pp = (const ull*)pin + repoff + 2 * tid;
        ull v0 = __hip_atomic_load(&pp[0], __ATOMIC_RELAXED, __HIP_MEMORY_SCOPE_AGENT);
        ull v1 = __hip_atomic_load(&pp[1], __ATOMIC_RELAXED, __HIP_MEMORY_SCOPE_AGENT);
        while (((v0 ^ tg2) | (v1 ^ tg2)) & M2) {
            __builtin_amdgcn_s_sleep(1);
            v0 = __hip_atomic_load(&pp[0], __ATOMIC_RELAXED, __HIP_MEMORY_SCOPE_AGENT);
            v1 = __hip_atomic_load(&pp[1], __ATOMIC_RELAXED, __HIP_MEMORY_SCOPE_AGENT);
        }
        float4 hq = make_float4(__uint_as_float((unsigned)v0         & ~TAGM),
                                __uint_as_float((unsigned)(v0 >> 32) & ~TAGM),
                                __uint_as_float((unsigned)v1         & ~TAGM),
                                __uint_as_float((unsigned)(v1 >> 32) & ~TAGM));
        *(float4*)&lds_h[lwb] = hq;
        __syncthreads();                          // BAR1: h_t staged

        float hold = 0.f;
        if (wv == 0) hold = lds_h[pcol];          // prefetch for finalize

        // ---- 96 register-resident FMAs ----
        float a0 = 0.f, a1 = 0.f, a2 = 0.f;
#pragma unroll
        for (int k = 0; k < 32; ++k) {
            float hv = lds_h[lrb + k];
            a0 = fmaf(hv, wr[k], a0);
            a1 = fmaf(hv, wz[k], a1);
            a2 = fmaf(hv, wn[k], a2);
        }
#pragma unroll
        for (int m = 8; m < 64; m <<= 1) {
            a0 += __shfl_xor(a0, m, 64);
            a1 += __shfl_xor(a1, m, 64);
            a2 += __shfl_xor(a2, m, 64);
        }
        if (lane < 8) { red[wv][0][lane]=a0; red[wv][1][lane]=a1; red[wv][2][lane]=a2; }
        __syncthreads();                          // BAR2: partials ready

        // ---- wave0: serial 24-read finalize (proven) + replicated publish ----
        if (wv == 0) {
            float hnew = 0.f; unsigned pk = 0;
            if (lane < 8) {
                float Sr=0, Sz=0, Sn=0;
#pragma unroll
                for (int w = 0; w < 8; ++w) {
                    Sr += red[w][0][lane]; Sz += red[w][1][lane]; Sn += red[w][2][lane];
                }
                float ar = aR + Sr;
                float az = aZ + Sz;
                float rg = sigmoid_f(ar), zg = sigmoid_f(az);
                float ng = tanh_f(aN + rg * (Sn + bhc));
                hnew = (1.f - zg) * ng + zg * hold;
                pk = ((__float_as_uint(hnew) + 512u) & ~TAGM)
                   | ((unsigned)(t + 1) & TAGM);
            }
            if (t == TSTEPS - 1) {
                if (lane < 8) out[col] = hnew;
            } else {
                unsigned pkb = __shfl(pk, lane & 7, 64);
                __hip_atomic_store(&pout[(unsigned)(lane >> 3) * RSTRIDE + (unsigned)blk * 8u + (unsigned)(lane & 7)],
                                   pkb, __ATOMIC_RELAXED, __HIP_MEMORY_SCOPE_AGENT);
                if (lane < 8) {   // precompute t+1 input terms (after publish)
                    float xn = sX[t + 1];
                    aR = fmaf(xn, vrc, crc);
                    aZ = fmaf(xn, vzc, czc);
                    aN = fmaf(xn, vnc, cnc);
                }
            }
        }
        __syncthreads();   // BAR3: publish issued before anyone spins on t+1
    }
}

extern "C" void kernel_launch(void* const* d_in, const int* in_sizes, int n_in,
                              void* d_out, int out_size, void* d_ws, size_t ws_size,
                              hipStream_t stream) {
    const float* x    = (const float*)d_in[0];
    const float* We   = (const float*)d_in[1];
    const float* be   = (const float*)d_in[2];
    const float* Wir  = (const float*)d_in[3];
    const float* bir  = (const float*)d_in[4];
    const float* Wiz  = (const float*)d_in[5];
    const float* biz  = (const float*)d_in[6];
    const float* Win  = (const float*)d_in[7];
    const float* bin_ = (const float*)d_in[8];
    const float* Whr  = (const float*)d_in[9];
    const float* Whz  = (const float*)d_in[10];
    const float* Whn  = (const float*)d_in[11];
    const float* bhn  = (const float*)d_in[12];

    unsigned* u0 = (unsigned*)d_ws;             // even parity: 8 replicas
    unsigned* u1 = u0 + NREP * RSTRIDE;         // odd parity:  8 replicas
    // total workspace use: 2 * 8 * 2112 * 4B = 132 KB

    gru_all<<<NBLK, NTHR, 0, stream>>>(x, We, be, Wir, bir, Wiz, biz, Win, bin_,
                                       Whr, Whz, Whn, bhn,
                                       (float*)d_out, u0, u1);
}